// Round 10
// baseline (221.890 us; speedup 1.0000x reference)
//
#include <hip/hip_runtime.h>
#include <hip/hip_bf16.h>
#include <stdint.h>

// out[8192,4096] = x[8192,2048] @ WeffT^T ; WeffT built from W (4096,2048).
#define M_DIM 8192
#define K_DIM 2048
#define N_DIM 4096
#define BM 256
#define BN 256
#define BK 64
#define NT (K_DIM / BK)    // 32 K-tiles
#define NITER (NT / 2)     // 16 iterations, 2 K-tiles each

typedef __attribute__((ext_vector_type(8))) short bf16x8;
typedef __attribute__((ext_vector_type(4))) float f32x4;

__device__ __forceinline__ unsigned short f2bfu(float f) {
    __hip_bfloat16 h = __float2bfloat16(f);
    return __builtin_bit_cast(unsigned short, h);
}

// ---------------------------------------------------------------------------
// Prep: WeffT only (x is consumed fp32 directly by the GEMM now).
// Paired rows {2b, 2b+1}: 7 global streams per pair (proven R6).
// ---------------------------------------------------------------------------
__global__ __launch_bounds__(256) void prep_weff(const float* __restrict__ W,
                                                 unsigned short* __restrict__ wt) {
    __shared__ float row0[K_DIM];
    __shared__ float row1[K_DIM];
    const int o0 = blockIdx.x * 2;
    const float* w0 = W + (size_t)o0 * K_DIM;
    const float* w1 = W + (size_t)(o0 + 1) * K_DIM;
#pragma unroll
    for (int t = 0; t < 2; ++t) {
        ((float4*)row0)[threadIdx.x + 256 * t] = ((const float4*)w0)[threadIdx.x + 256 * t];
        ((float4*)row1)[threadIdx.x + 256 * t] = ((const float4*)w1)[threadIdx.x + 256 * t];
    }
    __syncthreads();

    const float* rF0 = W + (size_t)(N_DIM - 1 - o0) * K_DIM;
    const float* rF1 = W + (size_t)(N_DIM - 2 - o0) * K_DIM;
    const float* rm1 = W + (size_t)((o0 - 1) & (N_DIM - 1)) * K_DIM;
    const float* rm2 = W + (size_t)((o0 - 2) & (N_DIM - 1)) * K_DIM;
    const float* rm3 = W + (size_t)((o0 - 3) & (N_DIM - 1)) * K_DIM;
    const float* rm4 = W + (size_t)((o0 - 4) & (N_DIM - 1)) * K_DIM;
    const float* rm5 = W + (size_t)((o0 - 5) & (N_DIM - 1)) * K_DIM;
    unsigned short* wo0 = wt + (size_t)o0 * K_DIM;
    unsigned short* wo1 = wo0 + K_DIM;

#pragma unroll
    for (int t = 0; t < 2; ++t) {
        const int i0 = (threadIdx.x + 256 * t) * 4;
        const float4 vF0 = *(const float4*)(rF0 + i0);
        const float4 vF1 = *(const float4*)(rF1 + i0);
        const float4 v1  = *(const float4*)(rm1 + i0);
        const float4 v2  = *(const float4*)(rm2 + i0);
        const float4 v3  = *(const float4*)(rm3 + i0);
        const float4 v4  = *(const float4*)(rm4 + i0);
        const float4 v5  = *(const float4*)(rm5 + i0);
        ushort4 ov0, ov1;
#pragma unroll
        for (int j = 0; j < 4; ++j) {
            const int i = i0 + j;
            float s0 = row0[i] + row0[K_DIM - 1 - i]
                     + row0[(i - 1) & (K_DIM - 1)] + row0[(i - 2) & (K_DIM - 1)]
                     + row0[(i - 3) & (K_DIM - 1)] + row0[(i - 4) & (K_DIM - 1)]
                     + row0[(i - 5) & (K_DIM - 1)];
            s0 += (&vF0.x)[j] + (&v1.x)[j] + (&v2.x)[j]
                + (&v3.x)[j] + (&v4.x)[j] + (&v5.x)[j];
            (&ov0.x)[j] = f2bfu(s0);

            float s1 = row1[i] + row1[K_DIM - 1 - i]
                     + row1[(i - 1) & (K_DIM - 1)] + row1[(i - 2) & (K_DIM - 1)]
                     + row1[(i - 3) & (K_DIM - 1)] + row1[(i - 4) & (K_DIM - 1)]
                     + row1[(i - 5) & (K_DIM - 1)];
            s1 += (&vF1.x)[j] + row0[i] + (&v1.x)[j] + (&v2.x)[j]
                + (&v3.x)[j] + (&v4.x)[j];
            (&ov1.x)[j] = f2bfu(s1);
        }
        *(ushort4*)(wo0 + i0) = ov0;
        *(ushort4*)(wo1 + i0) = ov1;
    }
}

// ---------------------------------------------------------------------------
// GEMM R10: A read DIRECTLY from x (fp32) via reg-staging + in-register
// bf16 convert + swizzled ds_write. B path / MFMA / read swizzle / barriers
// unchanged from the proven R6 core. Persistent 2 tiles/block (grid 256).
//
// LDS per buffer p (64 KiB @ p*65536): A @0 (A0 rows0-127, A1 @16384),
// B @32768 (B0, B1 @49152). Row=128B=8x16B slots, phys slot = logical^(row&7).
// A-writes now per-lane ds_write at the swizzled slot (read side identical).
//
// A pipeline (thread: row lwr=tid>>2 of a 128-row half, 16 consecutive f32 =
// slots s0=(tid&3)*2, s0+1):
//   issue 4 x global_load_dwordx4 at the A slot-phases (ph1:A1(t1), ph4:A0(t2),
//   ph5:A1(t2), ph8:A0(t3)); convert+write 2 phases later at ph3/ph7 under a
//   counted vmcnt(4), followed by lgkmcnt(0) before the publishing barrier.
// Ledger (steady, outstanding VMEM ops): ph3-end 16 -> vmcnt(4) forces
// {t1.B, t1.A0-loads, t1.A1-loads}, leaves t2.B(4); ph7-end 16 -> vmcnt(4)
// forces {t2.B, t2.A0, t2.A1}, leaves t3.B(4). Last iter: ph3 vmcnt(0),
// all later stages guarded out -> queue empty at tile end.
// Prologue: issue t0.A0,A1; gload t0.B, t1.B; vmcnt(4) (forces t0.*);
// write t0.A; lgkm0; issue t1.A0; barrier.
// ---------------------------------------------------------------------------
__global__ __launch_bounds__(512, 2) void gemm8p(const float* __restrict__ X,
                                                 const unsigned short* __restrict__ Bt,
                                                 float* __restrict__ C) {
    __shared__ __align__(16) char smem[2 * 65536];

    const int tid  = threadIdx.x;
    const int wave = tid >> 6;
    const int lane = tid & 63;

    // XCD-bijective swizzle (nwg = 256, % 8 == 0)
    const int cpx = 256 >> 3;
    const int wg  = ((int)blockIdx.x & 7) * cpx + ((int)blockIdx.x >> 3);

    const int wr = wave >> 2;                   // 0..1 (M)
    const int wc = wave & 3;                    // 0..3 (N)

    // ---- B staging (pre-swizzled global source, gload_lds; unchanged) ----
    const int srow = tid >> 3;
    const int lsw  = (lane & 7) ^ ((lane >> 3) & 7);

    // ---- A reg-staging geometry ----
    const int lwr = tid >> 2;                   // 0..127 (row within half)
    const int s0  = (tid & 3) * 2;              // first logical slot
    const int ps0 = (s0     ) ^ (lwr & 7);      // phys slot for write
    const int ps1 = (s0 + 1 ) ^ (lwr & 7);

    // ---- ds_read addressing (swizzled; conflict-free, proven) ----
    const int r16  = lane & 15;
    const int x7   = lane & 7;
    const int ksl0 = (((lane >> 4)    ) ^ x7) * 16;
    const int ksl1 = (((lane >> 4) | 4) ^ x7) * 16;
    const int aRow = (wr * 128 + r16) * 128;
    const int bRow = (wc * 64  + r16) * 128 + 32768;
    const int crow = (lane >> 4) * 4;
    const int ccol = lane & 15;

    f32x4  acc[8][4];
    bf16x8 b[4][2];
    float4 a0r0, a0r1, a0r2, a0r3;   // A0-half pipeline regs
    float4 a1r0, a1r1, a1r2, a1r3;   // A1-half pipeline regs
    const float* gAx;                 // per-tile A base (row lwr, col (tid&3)*16)
    const unsigned short* gB0;

#define STAGE_HALF(gbase, opoff, h, t, p) do {                                              \
    char* lds_ = smem + (p) * 65536 + (opoff) + (h) * 16384 + wave * 1024;                  \
    const unsigned short* g_ = (gbase) + (size_t)((h) * 128) * K_DIM + (t) * BK;            \
    __builtin_amdgcn_global_load_lds(                                                        \
        (const __attribute__((address_space(1))) unsigned int*)g_,                           \
        (__attribute__((address_space(3))) unsigned int*)lds_, 16, 0, 0);                    \
    __builtin_amdgcn_global_load_lds(                                                        \
        (const __attribute__((address_space(1))) unsigned int*)(g_ + (size_t)64 * K_DIM),    \
        (__attribute__((address_space(3))) unsigned int*)(lds_ + 8192), 16, 0, 0);           \
} while (0)

// issue 4 x dwordx4 fp32 loads for A half h of K-tile t into rp0..rp3
#define A_ISSUE(rp0, rp1, rp2, rp3, h, t) do {                                              \
    const float* g_ = gAx + (size_t)((h) * 128) * K_DIM + (t) * BK;                         \
    rp0 = *(const float4*)(g_);                                                             \
    rp1 = *(const float4*)(g_ + 4);                                                         \
    rp2 = *(const float4*)(g_ + 8);                                                         \
    rp3 = *(const float4*)(g_ + 12);                                                        \
} while (0)

// convert 16 f32 -> 16 bf16, write 2 swizzled 16B slots into buf p, half h
#define A_WRITE(rp0, rp1, rp2, rp3, h, p) do {                                              \
    unsigned int w0_ = ((unsigned)f2bfu(rp0.y) << 16) | f2bfu(rp0.x);                       \
    unsigned int w1_ = ((unsigned)f2bfu(rp0.w) << 16) | f2bfu(rp0.z);                       \
    unsigned int w2_ = ((unsigned)f2bfu(rp1.y) << 16) | f2bfu(rp1.x);                       \
    unsigned int w3_ = ((unsigned)f2bfu(rp1.w) << 16) | f2bfu(rp1.z);                       \
    unsigned int w4_ = ((unsigned)f2bfu(rp2.y) << 16) | f2bfu(rp2.x);                       \
    unsigned int w5_ = ((unsigned)f2bfu(rp2.w) << 16) | f2bfu(rp2.z);                       \
    unsigned int w6_ = ((unsigned)f2bfu(rp3.y) << 16) | f2bfu(rp3.x);                       \
    unsigned int w7_ = ((unsigned)f2bfu(rp3.w) << 16) | f2bfu(rp3.z);                       \
    char* la_ = smem + (p) * 65536 + (h) * 16384 + lwr * 128;                               \
    *(uint4*)(la_ + ps0 * 16) = (uint4){w0_, w1_, w2_, w3_};                                \
    *(uint4*)(la_ + ps1 * 16) = (uint4){w4_, w5_, w6_, w7_};                                \
} while (0)

#define PHASE(P, Q, LOADB, STAGE_STMT, VM_STMT) do {                                        \
    const char* base_ = smem + (P) * 65536;                                                 \
    bf16x8 a_[2][2];                                                                        \
    if (LOADB) {                                                                            \
        _Pragma("unroll")                                                                   \
        for (int fn = 0; fn < 4; ++fn) {                                                    \
            b[fn][0] = *(const bf16x8*)(base_ + bRow + fn * 2048 + ksl0);                   \
            b[fn][1] = *(const bf16x8*)(base_ + bRow + fn * 2048 + ksl1);                   \
        }                                                                                   \
    }                                                                                       \
    a_[0][0] = *(const bf16x8*)(base_ + aRow + (Q) * 4096 + ksl0);                          \
    a_[0][1] = *(const bf16x8*)(base_ + aRow + (Q) * 4096 + ksl1);                          \
    a_[1][0] = *(const bf16x8*)(base_ + aRow + (Q) * 4096 + 2048 + ksl0);                   \
    a_[1][1] = *(const bf16x8*)(base_ + aRow + (Q) * 4096 + 2048 + ksl1);                   \
    STAGE_STMT;                                                                             \
    __builtin_amdgcn_s_barrier();                                                           \
    asm volatile("s_waitcnt lgkmcnt(0)" ::: "memory");                                      \
    __builtin_amdgcn_sched_barrier(0);                                                      \
    __builtin_amdgcn_s_setprio(1);                                                          \
    _Pragma("unroll")                                                                       \
    for (int fm = 0; fm < 2; ++fm)                                                          \
        _Pragma("unroll")                                                                   \
        for (int fn = 0; fn < 4; ++fn) {                                                    \
            acc[(Q)*2 + fm][fn] = __builtin_amdgcn_mfma_f32_16x16x32_bf16(                  \
                a_[fm][0], b[fn][0], acc[(Q)*2 + fm][fn], 0, 0, 0);                         \
            acc[(Q)*2 + fm][fn] = __builtin_amdgcn_mfma_f32_16x16x32_bf16(                  \
                a_[fm][1], b[fn][1], acc[(Q)*2 + fm][fn], 0, 0, 0);                         \
        }                                                                                   \
    __builtin_amdgcn_s_setprio(0);                                                          \
    VM_STMT;                                                                                \
    __builtin_amdgcn_s_barrier();                                                           \
} while (0)

#define PROLOGUE() do {                                                                     \
    A_ISSUE(a0r0, a0r1, a0r2, a0r3, 0, 0);            /* t0.A0 */                           \
    A_ISSUE(a1r0, a1r1, a1r2, a1r3, 1, 0);            /* t0.A1 */                           \
    STAGE_HALF(gB0, 32768, 0, 0, 0);                                                        \
    STAGE_HALF(gB0, 32768, 1, 0, 0);                  /* t0.B  */                           \
    STAGE_HALF(gB0, 32768, 0, 1, 1);                                                        \
    STAGE_HALF(gB0, 32768, 1, 1, 1);                  /* t1.B  */                           \
    asm volatile("s_waitcnt vmcnt(4)" ::: "memory");  /* force t0.*, leave t1.B */          \
    A_WRITE(a0r0, a0r1, a0r2, a0r3, 0, 0);                                                  \
    A_WRITE(a1r0, a1r1, a1r2, a1r3, 1, 0);                                                  \
    asm volatile("s_waitcnt lgkmcnt(0)" ::: "memory");                                      \
    A_ISSUE(a0r0, a0r1, a0r2, a0r3, 0, 1);            /* t1.A0 */                           \
    __builtin_amdgcn_s_barrier();                                                           \
} while (0)

#define KLOOP() do {                                                                        \
    for (int u = 0; u < NITER; ++u) {                                                       \
        const bool last = (u == NITER - 1);                                                 \
        const int  t1 = 2 * u + 1, t2 = 2 * u + 2, t3 = 2 * u + 3;                          \
        PHASE(0, 0, 1, { A_ISSUE(a1r0, a1r1, a1r2, a1r3, 1, t1); }, {});                    \
        PHASE(0, 1, 0, { if (!last) STAGE_HALF(gB0, 32768, 0, t2, 0); }, {});               \
        PHASE(0, 2, 0, { if (!last) STAGE_HALF(gB0, 32768, 1, t2, 0); },                    \
              { if (last) asm volatile("s_waitcnt vmcnt(0)" ::: "memory");                  \
                else      asm volatile("s_waitcnt vmcnt(4)" ::: "memory");                  \
                A_WRITE(a0r0, a0r1, a0r2, a0r3, 0, 1);                                      \
                A_WRITE(a1r0, a1r1, a1r2, a1r3, 1, 1);                                      \
                asm volatile("s_waitcnt lgkmcnt(0)" ::: "memory"); });                      \
        PHASE(0, 3, 0, { if (!last) A_ISSUE(a0r0, a0r1, a0r2, a0r3, 0, t2); }, {});         \
        PHASE(1, 0, 1, { if (!last) A_ISSUE(a1r0, a1r1, a1r2, a1r3, 1, t2); }, {});         \
        PHASE(1, 1, 0, { if (!last) STAGE_HALF(gB0, 32768, 0, t3, 1); }, {});               \
        PHASE(1, 2, 0, { if (!last) STAGE_HALF(gB0, 32768, 1, t3, 1); },                    \
              { if (!last) {                                                                \
                    asm volatile("s_waitcnt vmcnt(4)" ::: "memory");                        \
                    A_WRITE(a0r0, a0r1, a0r2, a0r3, 0, 0);                                  \
                    A_WRITE(a1r0, a1r1, a1r2, a1r3, 1, 0);                                  \
                    asm volatile("s_waitcnt lgkmcnt(0)" ::: "memory"); } });                \
        PHASE(1, 3, 0, { if (!last) A_ISSUE(a0r0, a0r1, a0r2, a0r3, 0, t3); }, {});         \
    }                                                                                       \
} while (0)

#define CSTORE(Cb) do {                                                                     \
    _Pragma("unroll")                                                                       \
    for (int fm = 0; fm < 8; ++fm)                                                          \
        _Pragma("unroll")                                                                   \
        for (int fn = 0; fn < 4; ++fn)                                                      \
            _Pragma("unroll")                                                               \
            for (int r = 0; r < 4; ++r)                                                     \
                (Cb)[(size_t)(fm * 16 + r) * N_DIM + fn * 16] = acc[fm][fn][r];             \
} while (0)

#define ZERO_ACC() do {                                                                     \
    _Pragma("unroll")                                                                       \
    for (int i_ = 0; i_ < 8; ++i_)                                                          \
        _Pragma("unroll")                                                                   \
        for (int j_ = 0; j_ < 4; ++j_)                                                      \
            acc[i_][j_] = (f32x4){0.f, 0.f, 0.f, 0.f};                                      \
} while (0)

    // ================= tile 0 =================
    int bm0 = (wg >> 4) * BM;
    int bn0 = (wg & 15) * BN;
    gAx = X + (size_t)(bm0 + lwr) * K_DIM + (tid & 3) * 16;
    gB0 = Bt + (size_t)(bn0 + srow) * K_DIM + lsw * 8;
    float* Cb0 = C + (size_t)(bm0 + wr * 128 + crow) * N_DIM + (bn0 + wc * 64 + ccol);

    PROLOGUE();
    ZERO_ACC();
    KLOOP();

    // ================= tile 1 (same bn0, bm0 += 4096; B-panel L2-warm) =====
    bm0 += 4096;
    gAx = X + (size_t)(bm0 + lwr) * K_DIM + (tid & 3) * 16;
    float* Cb1 = C + (size_t)(bm0 + wr * 128 + crow) * N_DIM + (bn0 + wc * 64 + ccol);

    PROLOGUE();          // queue empty at tile0 end -> counts clean
    CSTORE(Cb0);         // stores drain under tile1's first phases
    ZERO_ACC();
    KLOOP();
    CSTORE(Cb1);

#undef CSTORE
#undef ZERO_ACC
#undef KLOOP
#undef PROLOGUE
#undef PHASE
#undef A_WRITE
#undef A_ISSUE
#undef STAGE_HALF
}

// ---------------------------------------------------------------------------
extern "C" void kernel_launch(void* const* d_in, const int* in_sizes, int n_in,
                              void* d_out, int out_size, void* d_ws, size_t ws_size,
                              hipStream_t stream) {
    const float* x = (const float*)d_in[0];   // (4,2048,2048) fp32
    const float* W = (const float*)d_in[1];   // (4096,2048) fp32
    float* out = (float*)d_out;               // (4,2048,4096) fp32

    unsigned short* wt = (unsigned short*)d_ws;   // 16 MB WeffT (only ws use now)

    prep_weff<<<N_DIM / 2, 256, 0, stream>>>(W, wt);
    gemm8p<<<256, 512, 0, stream>>>(x, wt, out);  // persistent: 2 tiles/block
}

// Round 11
// 161.878 us; speedup vs baseline: 1.3707x; 1.3707x over previous
//
#include <hip/hip_runtime.h>
#include <hip/hip_bf16.h>
#include <stdint.h>

// out[8192,4096] = x[8192,2048] @ WeffT^T ; WeffT built from W (4096,2048).
#define M_DIM 8192
#define K_DIM 2048
#define N_DIM 4096
#define BM 256
#define BN 256
#define BK 64
#define NT (K_DIM / BK)    // 32 K-tiles
#define NITER (NT / 2)     // 16 iterations, 2 K-tiles each

typedef __attribute__((ext_vector_type(8))) short bf16x8;
typedef __attribute__((ext_vector_type(4))) float f32x4;

__device__ __forceinline__ unsigned short f2bfu(float f) {
    __hip_bfloat16 h = __float2bfloat16(f);
    return __builtin_bit_cast(unsigned short, h);
}

// ---------------------------------------------------------------------------
// Fused prep (one dispatch), unchanged from R6 (measured ~35 us = HBM floor):
//   blocks [0, 2048):  WeffT rows {2b, 2b+1} (paired streams)
//   blocks [2048, 2048+16384): x fp32 -> bf16
// ---------------------------------------------------------------------------
__global__ __launch_bounds__(256) void prep_fused(const float* __restrict__ x,
                                                  const float* __restrict__ W,
                                                  unsigned short* __restrict__ xb,
                                                  unsigned short* __restrict__ wt) {
    const int bid = blockIdx.x;
    if (bid < N_DIM / 2) {
        __shared__ float row0[K_DIM];
        __shared__ float row1[K_DIM];
        const int o0 = bid * 2;
        const float* w0 = W + (size_t)o0 * K_DIM;
        const float* w1 = W + (size_t)(o0 + 1) * K_DIM;
#pragma unroll
        for (int t = 0; t < 2; ++t) {
            ((float4*)row0)[threadIdx.x + 256 * t] = ((const float4*)w0)[threadIdx.x + 256 * t];
            ((float4*)row1)[threadIdx.x + 256 * t] = ((const float4*)w1)[threadIdx.x + 256 * t];
        }
        __syncthreads();

        const float* rF0 = W + (size_t)(N_DIM - 1 - o0) * K_DIM;
        const float* rF1 = W + (size_t)(N_DIM - 2 - o0) * K_DIM;
        const float* rm1 = W + (size_t)((o0 - 1) & (N_DIM - 1)) * K_DIM;
        const float* rm2 = W + (size_t)((o0 - 2) & (N_DIM - 1)) * K_DIM;
        const float* rm3 = W + (size_t)((o0 - 3) & (N_DIM - 1)) * K_DIM;
        const float* rm4 = W + (size_t)((o0 - 4) & (N_DIM - 1)) * K_DIM;
        const float* rm5 = W + (size_t)((o0 - 5) & (N_DIM - 1)) * K_DIM;
        unsigned short* wo0 = wt + (size_t)o0 * K_DIM;
        unsigned short* wo1 = wo0 + K_DIM;

#pragma unroll
        for (int t = 0; t < 2; ++t) {
            const int i0 = (threadIdx.x + 256 * t) * 4;
            const float4 vF0 = *(const float4*)(rF0 + i0);
            const float4 vF1 = *(const float4*)(rF1 + i0);
            const float4 v1  = *(const float4*)(rm1 + i0);
            const float4 v2  = *(const float4*)(rm2 + i0);
            const float4 v3  = *(const float4*)(rm3 + i0);
            const float4 v4  = *(const float4*)(rm4 + i0);
            const float4 v5  = *(const float4*)(rm5 + i0);
            ushort4 ov0, ov1;
#pragma unroll
            for (int j = 0; j < 4; ++j) {
                const int i = i0 + j;
                float s0 = row0[i] + row0[K_DIM - 1 - i]
                         + row0[(i - 1) & (K_DIM - 1)] + row0[(i - 2) & (K_DIM - 1)]
                         + row0[(i - 3) & (K_DIM - 1)] + row0[(i - 4) & (K_DIM - 1)]
                         + row0[(i - 5) & (K_DIM - 1)];
                s0 += (&vF0.x)[j] + (&v1.x)[j] + (&v2.x)[j]
                    + (&v3.x)[j] + (&v4.x)[j] + (&v5.x)[j];
                (&ov0.x)[j] = f2bfu(s0);

                float s1 = row1[i] + row1[K_DIM - 1 - i]
                         + row1[(i - 1) & (K_DIM - 1)] + row1[(i - 2) & (K_DIM - 1)]
                         + row1[(i - 3) & (K_DIM - 1)] + row1[(i - 4) & (K_DIM - 1)]
                         + row1[(i - 5) & (K_DIM - 1)];
                s1 += (&vF1.x)[j] + row0[i] + (&v1.x)[j] + (&v2.x)[j]
                    + (&v3.x)[j] + (&v4.x)[j];
                (&ov1.x)[j] = f2bfu(s1);
            }
            *(ushort4*)(wo0 + i0) = ov0;
            *(ushort4*)(wo1 + i0) = ov1;
        }
    } else {
        const int idx = (bid - N_DIM / 2) * 256 + threadIdx.x;
        float4 v = ((const float4*)x)[idx];
        ushort4 o;
        o.x = f2bfu(v.x); o.y = f2bfu(v.y); o.z = f2bfu(v.z); o.w = f2bfu(v.w);
        ((ushort4*)xb)[idx] = o;
    }
}

// ---------------------------------------------------------------------------
// GEMM R11 = R6 core (proven: 0 conflicts, 3-half-deep vmcnt(6)) with the
// last iteration PEELED: quadrant Q's C-stores issue right after the phase
// (5+Q) that finalizes it. After last-iter ph4's vmcnt(0) the VMEM queue is
// empty and phases 5-8 contain NO counted waits, so stores drain under the
// remaining MFMA phases without perturbing any vmcnt ledger (R9/R10 lesson:
// stores + counted vmcnt = poison; here there are none to poison).
//
// LDS per buffer p (64 KiB @ p*65536): A @0 (A0 rows0-127, A1 @16384),
// B @32768 (B0, B1 @49152). Row=128B=8x16B slots, physical slot =
// logical ^ (row&7), both-sides swizzle (rule #21).
//
// Steady-state stage ledger (iterations 0..NITER-2, unconditional):
//   ph1: t1.A1->buf1   ph2: t2.B0->buf0   ph3: t2.B1->buf0
//   ph4: t2.A0->buf0 + vmcnt(6)
//   ph5: t2.A1->buf0   ph6: t3.B0->buf1   ph7: t3.B1->buf1
//   ph8: t3.A0->buf1 + vmcnt(6)
// Prologue: t0.{B0,B1,A0,A1}, t1.{B0,B1,A0} + vmcnt(6).
// Last iter (peeled): ph1 stages t1.A1 only; ph4 vmcnt(0); ph5-8 store
// quadrants 0-3.
// ---------------------------------------------------------------------------
__global__ __launch_bounds__(512, 2) void gemm8p(const unsigned short* __restrict__ Ab,
                                                 const unsigned short* __restrict__ Bt,
                                                 float* __restrict__ C) {
    __shared__ __align__(16) char smem[2 * 65536];

    const int tid  = threadIdx.x;
    const int wave = tid >> 6;
    const int lane = tid & 63;

    // XCD-bijective swizzle (nwg = 512, % 8 == 0)
    const int nwg = gridDim.x;
    const int cpx = nwg >> 3;
    const int wg  = (blockIdx.x & 7) * cpx + (blockIdx.x >> 3);
    const int nbn = N_DIM / BN;                 // 16
    const int bm0 = (wg / nbn) * BM;
    const int bn0 = (wg % nbn) * BN;

    const int wr = wave >> 2;                   // 0..1 (M)
    const int wc = wave & 3;                    // 0..3 (N)

    // ---- staging (pre-swizzled global source) ----
    const int srow = tid >> 3;                          // row within 64-row chunk
    const int lsw  = (lane & 7) ^ ((lane >> 3) & 7);    // logical slot fetched
    const unsigned short* gA0 = Ab + (size_t)(bm0 + srow) * K_DIM + lsw * 8;
    const unsigned short* gB0 = Bt + (size_t)(bn0 + srow) * K_DIM + lsw * 8;

    // ---- ds_read addressing (swizzled; conflict-free, proven R3/R5/R6) ----
    const int r16  = lane & 15;
    const int x7   = lane & 7;
    const int ksl0 = (((lane >> 4)    ) ^ x7) * 16;     // kk=0 slot
    const int ksl1 = (((lane >> 4) | 4) ^ x7) * 16;     // kk=1 slot
    const int aRow = (wr * 128 + r16) * 128;            // byte offset, A region
    const int bRow = (wc * 64  + r16) * 128 + 32768;    // byte offset, B region
    const int crow = (lane >> 4) * 4;
    const int ccol = lane & 15;
    float* Cb = C + (size_t)(bm0 + wr * 128 + crow) * N_DIM + (bn0 + wc * 64 + ccol);

    f32x4  acc[8][4] = {};
    bf16x8 b[4][2];

#define STAGE_HALF(gbase, opoff, h, t, p) do {                                              \
    char* lds_ = smem + (p) * 65536 + (opoff) + (h) * 16384 + wave * 1024;                  \
    const unsigned short* g_ = (gbase) + (size_t)((h) * 128) * K_DIM + (t) * BK;            \
    __builtin_amdgcn_global_load_lds(                                                        \
        (const __attribute__((address_space(1))) unsigned int*)g_,                           \
        (__attribute__((address_space(3))) unsigned int*)lds_, 16, 0, 0);                    \
    __builtin_amdgcn_global_load_lds(                                                        \
        (const __attribute__((address_space(1))) unsigned int*)(g_ + (size_t)64 * K_DIM),    \
        (__attribute__((address_space(3))) unsigned int*)(lds_ + 8192), 16, 0, 0);           \
} while (0)

#define PHASE(P, Q, LOADB, STAGE_STMT, VM_STMT) do {                                        \
    const char* base_ = smem + (P) * 65536;                                                 \
    bf16x8 a_[2][2];                                                                        \
    if (LOADB) {                                                                            \
        _Pragma("unroll")                                                                   \
        for (int fn = 0; fn < 4; ++fn) {                                                    \
            b[fn][0] = *(const bf16x8*)(base_ + bRow + fn * 2048 + ksl0);                   \
            b[fn][1] = *(const bf16x8*)(base_ + bRow + fn * 2048 + ksl1);                   \
        }                                                                                   \
    }                                                                                       \
    a_[0][0] = *(const bf16x8*)(base_ + aRow + (Q) * 4096 + ksl0);                          \
    a_[0][1] = *(const bf16x8*)(base_ + aRow + (Q) * 4096 + ksl1);                          \
    a_[1][0] = *(const bf16x8*)(base_ + aRow + (Q) * 4096 + 2048 + ksl0);                   \
    a_[1][1] = *(const bf16x8*)(base_ + aRow + (Q) * 4096 + 2048 + ksl1);                   \
    STAGE_STMT;                                                                             \
    __builtin_amdgcn_s_barrier();                                                           \
    asm volatile("s_waitcnt lgkmcnt(0)" ::: "memory");                                      \
    __builtin_amdgcn_sched_barrier(0);                                                      \
    __builtin_amdgcn_s_setprio(1);                                                          \
    _Pragma("unroll")                                                                       \
    for (int fm = 0; fm < 2; ++fm)                                                          \
        _Pragma("unroll")                                                                   \
        for (int fn = 0; fn < 4; ++fn) {                                                    \
            acc[(Q)*2 + fm][fn] = __builtin_amdgcn_mfma_f32_16x16x32_bf16(                  \
                a_[fm][0], b[fn][0], acc[(Q)*2 + fm][fn], 0, 0, 0);                         \
            acc[(Q)*2 + fm][fn] = __builtin_amdgcn_mfma_f32_16x16x32_bf16(                  \
                a_[fm][1], b[fn][1], acc[(Q)*2 + fm][fn], 0, 0, 0);                         \
        }                                                                                   \
    __builtin_amdgcn_s_setprio(0);                                                          \
    VM_STMT;                                                                                \
    __builtin_amdgcn_s_barrier();                                                           \
} while (0)

// store quadrant Q (acc[2Q], acc[2Q+1]) — only used in peeled last iteration
// where the VMEM queue is empty and no counted waits follow.
#define STORE_Q(Q) do {                                                                     \
    _Pragma("unroll")                                                                       \
    for (int fm = (Q) * 2; fm < (Q) * 2 + 2; ++fm)                                          \
        _Pragma("unroll")                                                                   \
        for (int fn = 0; fn < 4; ++fn)                                                      \
            _Pragma("unroll")                                                               \
            for (int r = 0; r < 4; ++r)                                                     \
                Cb[(size_t)(fm * 16 + r) * N_DIM + fn * 16] = acc[fm][fn][r];               \
} while (0)

    // ---- prologue: t0 complete + t1.{B0,B1,A0}; newest 3 halves may fly ----
    STAGE_HALF(gB0, 32768, 0, 0, 0);
    STAGE_HALF(gB0, 32768, 1, 0, 0);
    STAGE_HALF(gA0, 0,     0, 0, 0);
    STAGE_HALF(gA0, 0,     1, 0, 0);
    STAGE_HALF(gB0, 32768, 0, 1, 1);
    STAGE_HALF(gB0, 32768, 1, 1, 1);
    STAGE_HALF(gA0, 0,     0, 1, 1);
    asm volatile("s_waitcnt vmcnt(6)" ::: "memory");
    __builtin_amdgcn_s_barrier();

    // ---- steady iterations (no tail branches) ----
    for (int u = 0; u < NITER - 1; ++u) {
        const int t1 = 2 * u + 1, t2 = 2 * u + 2, t3 = 2 * u + 3;

        PHASE(0, 0, 1, { STAGE_HALF(gA0, 0, 1, t1, 1); }, {});                 // t1.A1
        PHASE(0, 1, 0, { STAGE_HALF(gB0, 32768, 0, t2, 0); }, {});             // t2.B0
        PHASE(0, 2, 0, { STAGE_HALF(gB0, 32768, 1, t2, 0); }, {});             // t2.B1
        PHASE(0, 3, 0, { STAGE_HALF(gA0, 0, 0, t2, 0); },                      // t2.A0
              { asm volatile("s_waitcnt vmcnt(6)" ::: "memory"); });
        PHASE(1, 0, 1, { STAGE_HALF(gA0, 0, 1, t2, 0); }, {});                 // t2.A1
        PHASE(1, 1, 0, { STAGE_HALF(gB0, 32768, 0, t3, 1); }, {});             // t3.B0
        PHASE(1, 2, 0, { STAGE_HALF(gB0, 32768, 1, t3, 1); }, {});             // t3.B1
        PHASE(1, 3, 0, { STAGE_HALF(gA0, 0, 0, t3, 1); },                      // t3.A0
              { asm volatile("s_waitcnt vmcnt(6)" ::: "memory"); });
    }

    // ---- peeled last iteration: progressive quadrant stores in ph5-8 ----
    PHASE(0, 0, 1, { STAGE_HALF(gA0, 0, 1, NT - 1, 1); }, {});                 // final A1
    PHASE(0, 1, 0, {}, {});
    PHASE(0, 2, 0, {}, {});
    PHASE(0, 3, 0, {}, { asm volatile("s_waitcnt vmcnt(0)" ::: "memory"); });  // queue empty
    PHASE(1, 0, 1, {}, { STORE_Q(0); });
    PHASE(1, 1, 0, {}, { STORE_Q(1); });
    PHASE(1, 2, 0, {}, { STORE_Q(2); });
    PHASE(1, 3, 0, {}, { STORE_Q(3); });

#undef STORE_Q
#undef PHASE
#undef STAGE_HALF
}

// ---------------------------------------------------------------------------
extern "C" void kernel_launch(void* const* d_in, const int* in_sizes, int n_in,
                              void* d_out, int out_size, void* d_ws, size_t ws_size,
                              hipStream_t stream) {
    const float* x = (const float*)d_in[0];   // (4,2048,2048) fp32
    const float* W = (const float*)d_in[1];   // (4096,2048) fp32
    float* out = (float*)d_out;               // (4,2048,4096) fp32

    unsigned short* xb = (unsigned short*)d_ws;                                      // 32 MB bf16 x
    unsigned short* wt = (unsigned short*)((char*)d_ws + (size_t)M_DIM * K_DIM * 2); // 16 MB WeffT

    const int cvt_blocks = (M_DIM * K_DIM) / 4 / 256;   // 16384
    prep_fused<<<N_DIM / 2 + cvt_blocks, 256, 0, stream>>>(x, W, xb, wt);

    dim3 grid((M_DIM / BM) * (N_DIM / BN));   // 512 blocks
    gemm8p<<<grid, 512, 0, stream>>>(xb, wt, out);
}

// Round 12
// 159.313 us; speedup vs baseline: 1.3928x; 1.0161x over previous
//
#include <hip/hip_runtime.h>
#include <hip/hip_bf16.h>
#include <stdint.h>

// out[8192,4096] = x[8192,2048] @ WeffT^T ; WeffT built from W (4096,2048).
#define M_DIM 8192
#define K_DIM 2048
#define N_DIM 4096
#define BM 256
#define BN 256
#define BK 64
#define NT (K_DIM / BK)    // 32 K-tiles
#define NITER (NT / 2)     // 16 iterations, 2 K-tiles each

typedef __attribute__((ext_vector_type(8))) short bf16x8;
typedef __attribute__((ext_vector_type(4))) float f32x4;

__device__ __forceinline__ unsigned short f2bfu(float f) {
    __hip_bfloat16 h = __float2bfloat16(f);
    return __builtin_bit_cast(unsigned short, h);
}

// ---------------------------------------------------------------------------
// Fused prep v3 (one dispatch):
//   blocks [0, 2048):        WeffT rows {2b, 2b+1} (paired streams, proven R6)
//   blocks [2048, 2048+1024): x fp32 -> bf16, grid-stride fat blocks
//                             (4 x float4 per thread = 64B read / 32B write)
// ---------------------------------------------------------------------------
__global__ __launch_bounds__(256) void prep_fused(const float* __restrict__ x,
                                                  const float* __restrict__ W,
                                                  unsigned short* __restrict__ xb,
                                                  unsigned short* __restrict__ wt) {
    const int bid = blockIdx.x;
    if (bid < N_DIM / 2) {
        __shared__ float row0[K_DIM];
        __shared__ float row1[K_DIM];
        const int o0 = bid * 2;
        const float* w0 = W + (size_t)o0 * K_DIM;
        const float* w1 = W + (size_t)(o0 + 1) * K_DIM;
#pragma unroll
        for (int t = 0; t < 2; ++t) {
            ((float4*)row0)[threadIdx.x + 256 * t] = ((const float4*)w0)[threadIdx.x + 256 * t];
            ((float4*)row1)[threadIdx.x + 256 * t] = ((const float4*)w1)[threadIdx.x + 256 * t];
        }
        __syncthreads();

        const float* rF0 = W + (size_t)(N_DIM - 1 - o0) * K_DIM;
        const float* rF1 = W + (size_t)(N_DIM - 2 - o0) * K_DIM;
        const float* rm1 = W + (size_t)((o0 - 1) & (N_DIM - 1)) * K_DIM;
        const float* rm2 = W + (size_t)((o0 - 2) & (N_DIM - 1)) * K_DIM;
        const float* rm3 = W + (size_t)((o0 - 3) & (N_DIM - 1)) * K_DIM;
        const float* rm4 = W + (size_t)((o0 - 4) & (N_DIM - 1)) * K_DIM;
        const float* rm5 = W + (size_t)((o0 - 5) & (N_DIM - 1)) * K_DIM;
        unsigned short* wo0 = wt + (size_t)o0 * K_DIM;
        unsigned short* wo1 = wo0 + K_DIM;

#pragma unroll
        for (int t = 0; t < 2; ++t) {
            const int i0 = (threadIdx.x + 256 * t) * 4;
            const float4 vF0 = *(const float4*)(rF0 + i0);
            const float4 vF1 = *(const float4*)(rF1 + i0);
            const float4 v1  = *(const float4*)(rm1 + i0);
            const float4 v2  = *(const float4*)(rm2 + i0);
            const float4 v3  = *(const float4*)(rm3 + i0);
            const float4 v4  = *(const float4*)(rm4 + i0);
            const float4 v5  = *(const float4*)(rm5 + i0);
            ushort4 ov0, ov1;
#pragma unroll
            for (int j = 0; j < 4; ++j) {
                const int i = i0 + j;
                float s0 = row0[i] + row0[K_DIM - 1 - i]
                         + row0[(i - 1) & (K_DIM - 1)] + row0[(i - 2) & (K_DIM - 1)]
                         + row0[(i - 3) & (K_DIM - 1)] + row0[(i - 4) & (K_DIM - 1)]
                         + row0[(i - 5) & (K_DIM - 1)];
                s0 += (&vF0.x)[j] + (&v1.x)[j] + (&v2.x)[j]
                    + (&v3.x)[j] + (&v4.x)[j] + (&v5.x)[j];
                (&ov0.x)[j] = f2bfu(s0);

                float s1 = row1[i] + row1[K_DIM - 1 - i]
                         + row1[(i - 1) & (K_DIM - 1)] + row1[(i - 2) & (K_DIM - 1)]
                         + row1[(i - 3) & (K_DIM - 1)] + row1[(i - 4) & (K_DIM - 1)]
                         + row1[(i - 5) & (K_DIM - 1)];
                s1 += (&vF1.x)[j] + row0[i] + (&v1.x)[j] + (&v2.x)[j]
                    + (&v3.x)[j] + (&v4.x)[j];
                (&ov1.x)[j] = f2bfu(s1);
            }
            *(ushort4*)(wo0 + i0) = ov0;
            *(ushort4*)(wo1 + i0) = ov1;
        }
    } else {
        // cvt: 1024 fat blocks; thread handles 4 float4s, 4 loads in flight.
        const int cb  = bid - N_DIM / 2;              // 0..1023
        const int t4  = cb * 1024 + threadIdx.x;      // base float4 index
        const float4*  xin = (const float4*)x;
        ushort4*       xo  = (ushort4*)xb;
        float4 v0 = xin[t4];
        float4 v1 = xin[t4 + 256];
        float4 v2 = xin[t4 + 512];
        float4 v3 = xin[t4 + 768];
        ushort4 o0, o1, o2, o3;
        o0.x = f2bfu(v0.x); o0.y = f2bfu(v0.y); o0.z = f2bfu(v0.z); o0.w = f2bfu(v0.w);
        o1.x = f2bfu(v1.x); o1.y = f2bfu(v1.y); o1.z = f2bfu(v1.z); o1.w = f2bfu(v1.w);
        o2.x = f2bfu(v2.x); o2.y = f2bfu(v2.y); o2.z = f2bfu(v2.z); o2.w = f2bfu(v2.w);
        o3.x = f2bfu(v3.x); o3.y = f2bfu(v3.y); o3.z = f2bfu(v3.z); o3.w = f2bfu(v3.w);
        xo[t4]       = o0;
        xo[t4 + 256] = o1;
        xo[t4 + 512] = o2;
        xo[t4 + 768] = o3;
    }
}

// ---------------------------------------------------------------------------
// GEMM R12 = R11 verbatim (proven: 0 conflicts, 3-half-deep vmcnt(6),
// peeled last iteration with progressive quadrant stores).
// ---------------------------------------------------------------------------
__global__ __launch_bounds__(512, 2) void gemm8p(const unsigned short* __restrict__ Ab,
                                                 const unsigned short* __restrict__ Bt,
                                                 float* __restrict__ C) {
    __shared__ __align__(16) char smem[2 * 65536];

    const int tid  = threadIdx.x;
    const int wave = tid >> 6;
    const int lane = tid & 63;

    // XCD-bijective swizzle (nwg = 512, % 8 == 0)
    const int nwg = gridDim.x;
    const int cpx = nwg >> 3;
    const int wg  = (blockIdx.x & 7) * cpx + (blockIdx.x >> 3);
    const int nbn = N_DIM / BN;                 // 16
    const int bm0 = (wg / nbn) * BM;
    const int bn0 = (wg % nbn) * BN;

    const int wr = wave >> 2;                   // 0..1 (M)
    const int wc = wave & 3;                    // 0..3 (N)

    // ---- staging (pre-swizzled global source) ----
    const int srow = tid >> 3;                          // row within 64-row chunk
    const int lsw  = (lane & 7) ^ ((lane >> 3) & 7);    // logical slot fetched
    const unsigned short* gA0 = Ab + (size_t)(bm0 + srow) * K_DIM + lsw * 8;
    const unsigned short* gB0 = Bt + (size_t)(bn0 + srow) * K_DIM + lsw * 8;

    // ---- ds_read addressing (swizzled; conflict-free, proven) ----
    const int r16  = lane & 15;
    const int x7   = lane & 7;
    const int ksl0 = (((lane >> 4)    ) ^ x7) * 16;     // kk=0 slot
    const int ksl1 = (((lane >> 4) | 4) ^ x7) * 16;     // kk=1 slot
    const int aRow = (wr * 128 + r16) * 128;            // byte offset, A region
    const int bRow = (wc * 64  + r16) * 128 + 32768;    // byte offset, B region
    const int crow = (lane >> 4) * 4;
    const int ccol = lane & 15;
    float* Cb = C + (size_t)(bm0 + wr * 128 + crow) * N_DIM + (bn0 + wc * 64 + ccol);

    f32x4  acc[8][4] = {};
    bf16x8 b[4][2];

#define STAGE_HALF(gbase, opoff, h, t, p) do {                                              \
    char* lds_ = smem + (p) * 65536 + (opoff) + (h) * 16384 + wave * 1024;                  \
    const unsigned short* g_ = (gbase) + (size_t)((h) * 128) * K_DIM + (t) * BK;            \
    __builtin_amdgcn_global_load_lds(                                                        \
        (const __attribute__((address_space(1))) unsigned int*)g_,                           \
        (__attribute__((address_space(3))) unsigned int*)lds_, 16, 0, 0);                    \
    __builtin_amdgcn_global_load_lds(                                                        \
        (const __attribute__((address_space(1))) unsigned int*)(g_ + (size_t)64 * K_DIM),    \
        (__attribute__((address_space(3))) unsigned int*)(lds_ + 8192), 16, 0, 0);           \
} while (0)

#define PHASE(P, Q, LOADB, STAGE_STMT, VM_STMT) do {                                        \
    const char* base_ = smem + (P) * 65536;                                                 \
    bf16x8 a_[2][2];                                                                        \
    if (LOADB) {                                                                            \
        _Pragma("unroll")                                                                   \
        for (int fn = 0; fn < 4; ++fn) {                                                    \
            b[fn][0] = *(const bf16x8*)(base_ + bRow + fn * 2048 + ksl0);                   \
            b[fn][1] = *(const bf16x8*)(base_ + bRow + fn * 2048 + ksl1);                   \
        }                                                                                   \
    }                                                                                       \
    a_[0][0] = *(const bf16x8*)(base_ + aRow + (Q) * 4096 + ksl0);                          \
    a_[0][1] = *(const bf16x8*)(base_ + aRow + (Q) * 4096 + ksl1);                          \
    a_[1][0] = *(const bf16x8*)(base_ + aRow + (Q) * 4096 + 2048 + ksl0);                   \
    a_[1][1] = *(const bf16x8*)(base_ + aRow + (Q) * 4096 + 2048 + ksl1);                   \
    STAGE_STMT;                                                                             \
    __builtin_amdgcn_s_barrier();                                                           \
    asm volatile("s_waitcnt lgkmcnt(0)" ::: "memory");                                      \
    __builtin_amdgcn_sched_barrier(0);                                                      \
    __builtin_amdgcn_s_setprio(1);                                                          \
    _Pragma("unroll")                                                                       \
    for (int fm = 0; fm < 2; ++fm)                                                          \
        _Pragma("unroll")                                                                   \
        for (int fn = 0; fn < 4; ++fn) {                                                    \
            acc[(Q)*2 + fm][fn] = __builtin_amdgcn_mfma_f32_16x16x32_bf16(                  \
                a_[fm][0], b[fn][0], acc[(Q)*2 + fm][fn], 0, 0, 0);                         \
            acc[(Q)*2 + fm][fn] = __builtin_amdgcn_mfma_f32_16x16x32_bf16(                  \
                a_[fm][1], b[fn][1], acc[(Q)*2 + fm][fn], 0, 0, 0);                         \
        }                                                                                   \
    __builtin_amdgcn_s_setprio(0);                                                          \
    VM_STMT;                                                                                \
    __builtin_amdgcn_s_barrier();                                                           \
} while (0)

#define STORE_Q(Q) do {                                                                     \
    _Pragma("unroll")                                                                       \
    for (int fm = (Q) * 2; fm < (Q) * 2 + 2; ++fm)                                          \
        _Pragma("unroll")                                                                   \
        for (int fn = 0; fn < 4; ++fn)                                                      \
            _Pragma("unroll")                                                               \
            for (int r = 0; r < 4; ++r)                                                     \
                Cb[(size_t)(fm * 16 + r) * N_DIM + fn * 16] = acc[fm][fn][r];               \
} while (0)

    // ---- prologue: t0 complete + t1.{B0,B1,A0}; newest 3 halves may fly ----
    STAGE_HALF(gB0, 32768, 0, 0, 0);
    STAGE_HALF(gB0, 32768, 1, 0, 0);
    STAGE_HALF(gA0, 0,     0, 0, 0);
    STAGE_HALF(gA0, 0,     1, 0, 0);
    STAGE_HALF(gB0, 32768, 0, 1, 1);
    STAGE_HALF(gB0, 32768, 1, 1, 1);
    STAGE_HALF(gA0, 0,     0, 1, 1);
    asm volatile("s_waitcnt vmcnt(6)" ::: "memory");
    __builtin_amdgcn_s_barrier();

    // ---- steady iterations ----
    for (int u = 0; u < NITER - 1; ++u) {
        const int t1 = 2 * u + 1, t2 = 2 * u + 2, t3 = 2 * u + 3;

        PHASE(0, 0, 1, { STAGE_HALF(gA0, 0, 1, t1, 1); }, {});                 // t1.A1
        PHASE(0, 1, 0, { STAGE_HALF(gB0, 32768, 0, t2, 0); }, {});             // t2.B0
        PHASE(0, 2, 0, { STAGE_HALF(gB0, 32768, 1, t2, 0); }, {});             // t2.B1
        PHASE(0, 3, 0, { STAGE_HALF(gA0, 0, 0, t2, 0); },                      // t2.A0
              { asm volatile("s_waitcnt vmcnt(6)" ::: "memory"); });
        PHASE(1, 0, 1, { STAGE_HALF(gA0, 0, 1, t2, 0); }, {});                 // t2.A1
        PHASE(1, 1, 0, { STAGE_HALF(gB0, 32768, 0, t3, 1); }, {});             // t3.B0
        PHASE(1, 2, 0, { STAGE_HALF(gB0, 32768, 1, t3, 1); }, {});             // t3.B1
        PHASE(1, 3, 0, { STAGE_HALF(gA0, 0, 0, t3, 1); },                      // t3.A0
              { asm volatile("s_waitcnt vmcnt(6)" ::: "memory"); });
    }

    // ---- peeled last iteration: progressive quadrant stores in ph5-8 ----
    PHASE(0, 0, 1, { STAGE_HALF(gA0, 0, 1, NT - 1, 1); }, {});                 // final A1
    PHASE(0, 1, 0, {}, {});
    PHASE(0, 2, 0, {}, {});
    PHASE(0, 3, 0, {}, { asm volatile("s_waitcnt vmcnt(0)" ::: "memory"); });  // queue empty
    PHASE(1, 0, 1, {}, { STORE_Q(0); });
    PHASE(1, 1, 0, {}, { STORE_Q(1); });
    PHASE(1, 2, 0, {}, { STORE_Q(2); });
    PHASE(1, 3, 0, {}, { STORE_Q(3); });

#undef STORE_Q
#undef PHASE
#undef STAGE_HALF
}

// ---------------------------------------------------------------------------
extern "C" void kernel_launch(void* const* d_in, const int* in_sizes, int n_in,
                              void* d_out, int out_size, void* d_ws, size_t ws_size,
                              hipStream_t stream) {
    const float* x = (const float*)d_in[0];   // (4,2048,2048) fp32
    const float* W = (const float*)d_in[1];   // (4096,2048) fp32
    float* out = (float*)d_out;               // (4,2048,4096) fp32

    unsigned short* xb = (unsigned short*)d_ws;                                      // 32 MB bf16 x
    unsigned short* wt = (unsigned short*)((char*)d_ws + (size_t)M_DIM * K_DIM * 2); // 16 MB WeffT

    const int cvt_blocks = (M_DIM * K_DIM) / 4 / 256 / 4;   // 4096 f32/block -> 1024 blocks
    prep_fused<<<N_DIM / 2 + cvt_blocks, 256, 0, stream>>>(x, W, xb, wt);

    dim3 grid((M_DIM / BM) * (N_DIM / BN));   // 512 blocks
    gemm8p<<<grid, 512, 0, stream>>>(xb, wt, out);
}

// Round 13
// 153.908 us; speedup vs baseline: 1.4417x; 1.0351x over previous
//
#include <hip/hip_runtime.h>
#include <hip/hip_bf16.h>
#include <stdint.h>

// out[8192,4096] = x[8192,2048] @ WeffT^T ; WeffT built from W (4096,2048).
#define M_DIM 8192
#define K_DIM 2048
#define N_DIM 4096
#define BM 256
#define BN 256
#define BK 64
#define NT (K_DIM / BK)    // 32 K-tiles
#define NITER (NT / 2)     // 16 iterations, 2 K-tiles each

typedef __attribute__((ext_vector_type(8))) short bf16x8;
typedef __attribute__((ext_vector_type(4))) float f32x4;

__device__ __forceinline__ unsigned short f2bfu(float f) {
    __hip_bfloat16 h = __float2bfloat16(f);
    return __builtin_bit_cast(unsigned short, h);
}

// ---------------------------------------------------------------------------
// Fused prep v4 (one dispatch):
//   blocks [0, 1024):        WeffT rows {4b..4b+3} (4-row groups: 13 global
//                            streams per 4 rows vs 18 for paired — in-group
//                            axis-1 rolls come from LDS)
//   blocks [1024, 2048):     x fp32 -> bf16, fat blocks (4 x float4/thread)
// ---------------------------------------------------------------------------
__global__ __launch_bounds__(256) void prep_fused(const float* __restrict__ x,
                                                  const float* __restrict__ W,
                                                  unsigned short* __restrict__ xb,
                                                  unsigned short* __restrict__ wt) {
    const int bid = blockIdx.x;
    if (bid < N_DIM / 4) {
        __shared__ float rowl[4][K_DIM];
        const int o0 = bid * 4;
#pragma unroll
        for (int j = 0; j < 4; ++j) {
            const float* wj = W + (size_t)(o0 + j) * K_DIM;
#pragma unroll
            for (int t = 0; t < 2; ++t)
                ((float4*)rowl[j])[threadIdx.x + 256 * t] =
                    ((const float4*)wj)[threadIdx.x + 256 * t];
        }
        __syncthreads();

        // 9 global streams for the group: 4 flips + 5 axis-1 rolls
        const float* rF[4];
#pragma unroll
        for (int j = 0; j < 4; ++j)
            rF[j] = W + (size_t)(N_DIM - 1 - (o0 + j)) * K_DIM;
        const float* rm[5];
#pragma unroll
        for (int s = 0; s < 5; ++s)
            rm[s] = W + (size_t)((o0 - 1 - s) & (N_DIM - 1)) * K_DIM;

#pragma unroll
        for (int t = 0; t < 2; ++t) {
            const int i0 = (threadIdx.x + 256 * t) * 4;
            float4 vF[4], vm[5];
#pragma unroll
            for (int j = 0; j < 4; ++j) vF[j] = *(const float4*)(rF[j] + i0);
#pragma unroll
            for (int s = 0; s < 5; ++s) vm[s] = *(const float4*)(rm[s] + i0);

#pragma unroll
            for (int j = 0; j < 4; ++j) {
                ushort4 ov;
#pragma unroll
                for (int e = 0; e < 4; ++e) {
                    const int i = i0 + e;
                    const float* rj = rowl[j];
                    // axis-0 terms: own row + flip + 5 shifts (all LDS)
                    float s0 = rj[i] + rj[K_DIM - 1 - i]
                             + rj[(i - 1) & (K_DIM - 1)] + rj[(i - 2) & (K_DIM - 1)]
                             + rj[(i - 3) & (K_DIM - 1)] + rj[(i - 4) & (K_DIM - 1)]
                             + rj[(i - 5) & (K_DIM - 1)];
                    // axis-1 flip
                    s0 += (&vF[j].x)[e];
                    // axis-1 rolls s=1..5: rows o0+j-1 .. o0+j-5
                    //   in-group (o0..o0+j-1): LDS; below group: rm streams
#pragma unroll
                    for (int s = 1; s <= 5; ++s) {
                        const int src = j - s;          // group-relative row
                        if (src >= 0) s0 += rowl[src][i];
                        else          s0 += (&vm[-1 - src].x)[e];
                    }
                    (&ov.x)[e] = f2bfu(s0);
                }
                *(ushort4*)(wt + (size_t)(o0 + j) * K_DIM + i0) = ov;
            }
        }
    } else {
        // cvt: fat blocks; thread handles 4 float4s, 4 loads in flight.
        const int cb  = bid - N_DIM / 4;              // 0..1023
        const int t4  = cb * 1024 + threadIdx.x;      // base float4 index
        const float4*  xin = (const float4*)x;
        ushort4*       xo  = (ushort4*)xb;
        float4 v0 = xin[t4];
        float4 v1 = xin[t4 + 256];
        float4 v2 = xin[t4 + 512];
        float4 v3 = xin[t4 + 768];
        ushort4 o0, o1, o2, o3;
        o0.x = f2bfu(v0.x); o0.y = f2bfu(v0.y); o0.z = f2bfu(v0.z); o0.w = f2bfu(v0.w);
        o1.x = f2bfu(v1.x); o1.y = f2bfu(v1.y); o1.z = f2bfu(v1.z); o1.w = f2bfu(v1.w);
        o2.x = f2bfu(v2.x); o2.y = f2bfu(v2.y); o2.z = f2bfu(v2.z); o2.w = f2bfu(v2.w);
        o3.x = f2bfu(v3.x); o3.y = f2bfu(v3.y); o3.z = f2bfu(v3.z); o3.w = f2bfu(v3.w);
        xo[t4]       = o0;
        xo[t4 + 256] = o1;
        xo[t4 + 512] = o2;
        xo[t4 + 768] = o3;
    }
}

// ---------------------------------------------------------------------------
// GEMM R13 = R12/R11 verbatim (proven: 0 conflicts, 3-half-deep vmcnt(6),
// peeled last iteration with progressive quadrant stores).
// ---------------------------------------------------------------------------
__global__ __launch_bounds__(512, 2) void gemm8p(const unsigned short* __restrict__ Ab,
                                                 const unsigned short* __restrict__ Bt,
                                                 float* __restrict__ C) {
    __shared__ __align__(16) char smem[2 * 65536];

    const int tid  = threadIdx.x;
    const int wave = tid >> 6;
    const int lane = tid & 63;

    // XCD-bijective swizzle (nwg = 512, % 8 == 0)
    const int nwg = gridDim.x;
    const int cpx = nwg >> 3;
    const int wg  = (blockIdx.x & 7) * cpx + (blockIdx.x >> 3);
    const int nbn = N_DIM / BN;                 // 16
    const int bm0 = (wg / nbn) * BM;
    const int bn0 = (wg % nbn) * BN;

    const int wr = wave >> 2;                   // 0..1 (M)
    const int wc = wave & 3;                    // 0..3 (N)

    // ---- staging (pre-swizzled global source) ----
    const int srow = tid >> 3;                          // row within 64-row chunk
    const int lsw  = (lane & 7) ^ ((lane >> 3) & 7);    // logical slot fetched
    const unsigned short* gA0 = Ab + (size_t)(bm0 + srow) * K_DIM + lsw * 8;
    const unsigned short* gB0 = Bt + (size_t)(bn0 + srow) * K_DIM + lsw * 8;

    // ---- ds_read addressing (swizzled; conflict-free, proven) ----
    const int r16  = lane & 15;
    const int x7   = lane & 7;
    const int ksl0 = (((lane >> 4)    ) ^ x7) * 16;     // kk=0 slot
    const int ksl1 = (((lane >> 4) | 4) ^ x7) * 16;     // kk=1 slot
    const int aRow = (wr * 128 + r16) * 128;            // byte offset, A region
    const int bRow = (wc * 64  + r16) * 128 + 32768;    // byte offset, B region
    const int crow = (lane >> 4) * 4;
    const int ccol = lane & 15;
    float* Cb = C + (size_t)(bm0 + wr * 128 + crow) * N_DIM + (bn0 + wc * 64 + ccol);

    f32x4  acc[8][4] = {};
    bf16x8 b[4][2];

#define STAGE_HALF(gbase, opoff, h, t, p) do {                                              \
    char* lds_ = smem + (p) * 65536 + (opoff) + (h) * 16384 + wave * 1024;                  \
    const unsigned short* g_ = (gbase) + (size_t)((h) * 128) * K_DIM + (t) * BK;            \
    __builtin_amdgcn_global_load_lds(                                                        \
        (const __attribute__((address_space(1))) unsigned int*)g_,                           \
        (__attribute__((address_space(3))) unsigned int*)lds_, 16, 0, 0);                    \
    __builtin_amdgcn_global_load_lds(                                                        \
        (const __attribute__((address_space(1))) unsigned int*)(g_ + (size_t)64 * K_DIM),    \
        (__attribute__((address_space(3))) unsigned int*)(lds_ + 8192), 16, 0, 0);           \
} while (0)

#define PHASE(P, Q, LOADB, STAGE_STMT, VM_STMT) do {                                        \
    const char* base_ = smem + (P) * 65536;                                                 \
    bf16x8 a_[2][2];                                                                        \
    if (LOADB) {                                                                            \
        _Pragma("unroll")                                                                   \
        for (int fn = 0; fn < 4; ++fn) {                                                    \
            b[fn][0] = *(const bf16x8*)(base_ + bRow + fn * 2048 + ksl0);                   \
            b[fn][1] = *(const bf16x8*)(base_ + bRow + fn * 2048 + ksl1);                   \
        }                                                                                   \
    }                                                                                       \
    a_[0][0] = *(const bf16x8*)(base_ + aRow + (Q) * 4096 + ksl0);                          \
    a_[0][1] = *(const bf16x8*)(base_ + aRow + (Q) * 4096 + ksl1);                          \
    a_[1][0] = *(const bf16x8*)(base_ + aRow + (Q) * 4096 + 2048 + ksl0);                   \
    a_[1][1] = *(const bf16x8*)(base_ + aRow + (Q) * 4096 + 2048 + ksl1);                   \
    STAGE_STMT;                                                                             \
    __builtin_amdgcn_s_barrier();                                                           \
    asm volatile("s_waitcnt lgkmcnt(0)" ::: "memory");                                      \
    __builtin_amdgcn_sched_barrier(0);                                                      \
    __builtin_amdgcn_s_setprio(1);                                                          \
    _Pragma("unroll")                                                                       \
    for (int fm = 0; fm < 2; ++fm)                                                          \
        _Pragma("unroll")                                                                   \
        for (int fn = 0; fn < 4; ++fn) {                                                    \
            acc[(Q)*2 + fm][fn] = __builtin_amdgcn_mfma_f32_16x16x32_bf16(                  \
                a_[fm][0], b[fn][0], acc[(Q)*2 + fm][fn], 0, 0, 0);                         \
            acc[(Q)*2 + fm][fn] = __builtin_amdgcn_mfma_f32_16x16x32_bf16(                  \
                a_[fm][1], b[fn][1], acc[(Q)*2 + fm][fn], 0, 0, 0);                         \
        }                                                                                   \
    __builtin_amdgcn_s_setprio(0);                                                          \
    VM_STMT;                                                                                \
    __builtin_amdgcn_s_barrier();                                                           \
} while (0)

#define STORE_Q(Q) do {                                                                     \
    _Pragma("unroll")                                                                       \
    for (int fm = (Q) * 2; fm < (Q) * 2 + 2; ++fm)                                          \
        _Pragma("unroll")                                                                   \
        for (int fn = 0; fn < 4; ++fn)                                                      \
            _Pragma("unroll")                                                               \
            for (int r = 0; r < 4; ++r)                                                     \
                Cb[(size_t)(fm * 16 + r) * N_DIM + fn * 16] = acc[fm][fn][r];               \
} while (0)

    // ---- prologue: t0 complete + t1.{B0,B1,A0}; newest 3 halves may fly ----
    STAGE_HALF(gB0, 32768, 0, 0, 0);
    STAGE_HALF(gB0, 32768, 1, 0, 0);
    STAGE_HALF(gA0, 0,     0, 0, 0);
    STAGE_HALF(gA0, 0,     1, 0, 0);
    STAGE_HALF(gB0, 32768, 0, 1, 1);
    STAGE_HALF(gB0, 32768, 1, 1, 1);
    STAGE_HALF(gA0, 0,     0, 1, 1);
    asm volatile("s_waitcnt vmcnt(6)" ::: "memory");
    __builtin_amdgcn_s_barrier();

    // ---- steady iterations ----
    for (int u = 0; u < NITER - 1; ++u) {
        const int t1 = 2 * u + 1, t2 = 2 * u + 2, t3 = 2 * u + 3;

        PHASE(0, 0, 1, { STAGE_HALF(gA0, 0, 1, t1, 1); }, {});                 // t1.A1
        PHASE(0, 1, 0, { STAGE_HALF(gB0, 32768, 0, t2, 0); }, {});             // t2.B0
        PHASE(0, 2, 0, { STAGE_HALF(gB0, 32768, 1, t2, 0); }, {});             // t2.B1
        PHASE(0, 3, 0, { STAGE_HALF(gA0, 0, 0, t2, 0); },                      // t2.A0
              { asm volatile("s_waitcnt vmcnt(6)" ::: "memory"); });
        PHASE(1, 0, 1, { STAGE_HALF(gA0, 0, 1, t2, 0); }, {});                 // t2.A1
        PHASE(1, 1, 0, { STAGE_HALF(gB0, 32768, 0, t3, 1); }, {});             // t3.B0
        PHASE(1, 2, 0, { STAGE_HALF(gB0, 32768, 1, t3, 1); }, {});             // t3.B1
        PHASE(1, 3, 0, { STAGE_HALF(gA0, 0, 0, t3, 1); },                      // t3.A0
              { asm volatile("s_waitcnt vmcnt(6)" ::: "memory"); });
    }

    // ---- peeled last iteration: progressive quadrant stores in ph5-8 ----
    PHASE(0, 0, 1, { STAGE_HALF(gA0, 0, 1, NT - 1, 1); }, {});                 // final A1
    PHASE(0, 1, 0, {}, {});
    PHASE(0, 2, 0, {}, {});
    PHASE(0, 3, 0, {}, { asm volatile("s_waitcnt vmcnt(0)" ::: "memory"); });  // queue empty
    PHASE(1, 0, 1, {}, { STORE_Q(0); });
    PHASE(1, 1, 0, {}, { STORE_Q(1); });
    PHASE(1, 2, 0, {}, { STORE_Q(2); });
    PHASE(1, 3, 0, {}, { STORE_Q(3); });

#undef STORE_Q
#undef PHASE
#undef STAGE_HALF
}

// ---------------------------------------------------------------------------
extern "C" void kernel_launch(void* const* d_in, const int* in_sizes, int n_in,
                              void* d_out, int out_size, void* d_ws, size_t ws_size,
                              hipStream_t stream) {
    const float* x = (const float*)d_in[0];   // (4,2048,2048) fp32
    const float* W = (const float*)d_in[1];   // (4096,2048) fp32
    float* out = (float*)d_out;               // (4,2048,4096) fp32

    unsigned short* xb = (unsigned short*)d_ws;                                      // 32 MB bf16 x
    unsigned short* wt = (unsigned short*)((char*)d_ws + (size_t)M_DIM * K_DIM * 2); // 16 MB WeffT

    const int cvt_blocks = (M_DIM * K_DIM) / 4 / 256 / 4;   // 1024 fat blocks
    prep_fused<<<N_DIM / 4 + cvt_blocks, 256, 0, stream>>>(x, W, xb, wt);

    dim3 grid((M_DIM / BM) * (N_DIM / BN));   // 512 blocks
    gemm8p<<<grid, 512, 0, stream>>>(xb, wt, out);
}

// Round 14
// 152.056 us; speedup vs baseline: 1.4593x; 1.0122x over previous
//
#include <hip/hip_runtime.h>
#include <hip/hip_bf16.h>
#include <stdint.h>

// out[8192,4096] = x[8192,2048] @ WeffT^T ; WeffT built from W (4096,2048).
#define M_DIM 8192
#define K_DIM 2048
#define N_DIM 4096
#define BM 256
#define BN 256
#define BK 64
#define NT (K_DIM / BK)    // 32 K-tiles
#define NITER (NT / 2)     // 16 iterations, 2 K-tiles each

typedef __attribute__((ext_vector_type(8))) short bf16x8;
typedef __attribute__((ext_vector_type(4))) float f32x4;

__device__ __forceinline__ unsigned short f2bfu(float f) {
    __hip_bfloat16 h = __float2bfloat16(f);
    return __builtin_bit_cast(unsigned short, h);
}

// ---------------------------------------------------------------------------
// Fused prep v5 (one dispatch):
//   blocks [0, 512):       WeffT rows {8b..8b+7} (8-row groups: 21 streams
//                          per 8 rows — 8 own rows via LDS, 8 flips, 5 shared
//                          axis-0 rolls; in-group axis-1 rolls from LDS)
//   blocks [512, 1536):    x fp32 -> bf16, fat blocks (4 x float4/thread)
// ---------------------------------------------------------------------------
__global__ __launch_bounds__(256) void prep_fused(const float* __restrict__ x,
                                                  const float* __restrict__ W,
                                                  unsigned short* __restrict__ xb,
                                                  unsigned short* __restrict__ wt) {
    const int bid = blockIdx.x;
    if (bid < N_DIM / 8) {
        __shared__ float rowl[8][K_DIM];          // 64 KB
        const int o0 = bid * 8;
#pragma unroll
        for (int j = 0; j < 8; ++j) {
            const float* wj = W + (size_t)(o0 + j) * K_DIM;
#pragma unroll
            for (int t = 0; t < 2; ++t)
                ((float4*)rowl[j])[threadIdx.x + 256 * t] =
                    ((const float4*)wj)[threadIdx.x + 256 * t];
        }
        __syncthreads();

        // 13 global streams for the group: 8 flips + 5 axis-0 rolls
        const float* rF[8];
#pragma unroll
        for (int j = 0; j < 8; ++j)
            rF[j] = W + (size_t)(N_DIM - 1 - (o0 + j)) * K_DIM;
        const float* rm[5];
#pragma unroll
        for (int s = 0; s < 5; ++s)
            rm[s] = W + (size_t)((o0 - 1 - s) & (N_DIM - 1)) * K_DIM;

#pragma unroll
        for (int t = 0; t < 2; ++t) {
            const int i0 = (threadIdx.x + 256 * t) * 4;
            float4 vm[5];
#pragma unroll
            for (int s = 0; s < 5; ++s) vm[s] = *(const float4*)(rm[s] + i0);

#pragma unroll
            for (int j = 0; j < 8; ++j) {
                const float4 vF = *(const float4*)(rF[j] + i0);
                ushort4 ov;
#pragma unroll
                for (int e = 0; e < 4; ++e) {
                    const int i = i0 + e;
                    const float* rj = rowl[j];
                    // axis-1 terms of own row: identity + flip + 5 shifts (LDS)
                    float s0 = rj[i] + rj[K_DIM - 1 - i]
                             + rj[(i - 1) & (K_DIM - 1)] + rj[(i - 2) & (K_DIM - 1)]
                             + rj[(i - 3) & (K_DIM - 1)] + rj[(i - 4) & (K_DIM - 1)]
                             + rj[(i - 5) & (K_DIM - 1)];
                    // axis-0 flip
                    s0 += (&vF.x)[e];
                    // axis-0 rolls s=1..5: rows o0+j-1 .. o0+j-5
                    //   in-group: LDS; below group: shared rm streams
#pragma unroll
                    for (int s = 1; s <= 5; ++s) {
                        const int src = j - s;
                        if (src >= 0) s0 += rowl[src][i];
                        else          s0 += (&vm[-1 - src].x)[e];
                    }
                    (&ov.x)[e] = f2bfu(s0);
                }
                *(ushort4*)(wt + (size_t)(o0 + j) * K_DIM + i0) = ov;
            }
        }
    } else {
        // cvt: fat blocks; thread handles 4 float4s, 4 loads in flight.
        const int cb  = bid - N_DIM / 8;              // 0..1023
        const int t4  = cb * 1024 + threadIdx.x;      // base float4 index
        const float4*  xin = (const float4*)x;
        ushort4*       xo  = (ushort4*)xb;
        float4 v0 = xin[t4];
        float4 v1 = xin[t4 + 256];
        float4 v2 = xin[t4 + 512];
        float4 v3 = xin[t4 + 768];
        ushort4 o0, o1, o2, o3;
        o0.x = f2bfu(v0.x); o0.y = f2bfu(v0.y); o0.z = f2bfu(v0.z); o0.w = f2bfu(v0.w);
        o1.x = f2bfu(v1.x); o1.y = f2bfu(v1.y); o1.z = f2bfu(v1.z); o1.w = f2bfu(v1.w);
        o2.x = f2bfu(v2.x); o2.y = f2bfu(v2.y); o2.z = f2bfu(v2.z); o2.w = f2bfu(v2.w);
        o3.x = f2bfu(v3.x); o3.y = f2bfu(v3.y); o3.z = f2bfu(v3.z); o3.w = f2bfu(v3.w);
        xo[t4]       = o0;
        xo[t4 + 256] = o1;
        xo[t4 + 512] = o2;
        xo[t4 + 768] = o3;
    }
}

// ---------------------------------------------------------------------------
// GEMM R14 = R13/R12/R11 verbatim (proven: 0 conflicts, 3-half-deep vmcnt(6),
// peeled last iteration with progressive quadrant stores).
// ---------------------------------------------------------------------------
__global__ __launch_bounds__(512, 2) void gemm8p(const unsigned short* __restrict__ Ab,
                                                 const unsigned short* __restrict__ Bt,
                                                 float* __restrict__ C) {
    __shared__ __align__(16) char smem[2 * 65536];

    const int tid  = threadIdx.x;
    const int wave = tid >> 6;
    const int lane = tid & 63;

    // XCD-bijective swizzle (nwg = 512, % 8 == 0)
    const int nwg = gridDim.x;
    const int cpx = nwg >> 3;
    const int wg  = (blockIdx.x & 7) * cpx + (blockIdx.x >> 3);
    const int nbn = N_DIM / BN;                 // 16
    const int bm0 = (wg / nbn) * BM;
    const int bn0 = (wg % nbn) * BN;

    const int wr = wave >> 2;                   // 0..1 (M)
    const int wc = wave & 3;                    // 0..3 (N)

    // ---- staging (pre-swizzled global source) ----
    const int srow = tid >> 3;                          // row within 64-row chunk
    const int lsw  = (lane & 7) ^ ((lane >> 3) & 7);    // logical slot fetched
    const unsigned short* gA0 = Ab + (size_t)(bm0 + srow) * K_DIM + lsw * 8;
    const unsigned short* gB0 = Bt + (size_t)(bn0 + srow) * K_DIM + lsw * 8;

    // ---- ds_read addressing (swizzled; conflict-free, proven) ----
    const int r16  = lane & 15;
    const int x7   = lane & 7;
    const int ksl0 = (((lane >> 4)    ) ^ x7) * 16;     // kk=0 slot
    const int ksl1 = (((lane >> 4) | 4) ^ x7) * 16;     // kk=1 slot
    const int aRow = (wr * 128 + r16) * 128;            // byte offset, A region
    const int bRow = (wc * 64  + r16) * 128 + 32768;    // byte offset, B region
    const int crow = (lane >> 4) * 4;
    const int ccol = lane & 15;
    float* Cb = C + (size_t)(bm0 + wr * 128 + crow) * N_DIM + (bn0 + wc * 64 + ccol);

    f32x4  acc[8][4] = {};
    bf16x8 b[4][2];

#define STAGE_HALF(gbase, opoff, h, t, p) do {                                              \
    char* lds_ = smem + (p) * 65536 + (opoff) + (h) * 16384 + wave * 1024;                  \
    const unsigned short* g_ = (gbase) + (size_t)((h) * 128) * K_DIM + (t) * BK;            \
    __builtin_amdgcn_global_load_lds(                                                        \
        (const __attribute__((address_space(1))) unsigned int*)g_,                           \
        (__attribute__((address_space(3))) unsigned int*)lds_, 16, 0, 0);                    \
    __builtin_amdgcn_global_load_lds(                                                        \
        (const __attribute__((address_space(1))) unsigned int*)(g_ + (size_t)64 * K_DIM),    \
        (__attribute__((address_space(3))) unsigned int*)(lds_ + 8192), 16, 0, 0);           \
} while (0)

#define PHASE(P, Q, LOADB, STAGE_STMT, VM_STMT) do {                                        \
    const char* base_ = smem + (P) * 65536;                                                 \
    bf16x8 a_[2][2];                                                                        \
    if (LOADB) {                                                                            \
        _Pragma("unroll")                                                                   \
        for (int fn = 0; fn < 4; ++fn) {                                                    \
            b[fn][0] = *(const bf16x8*)(base_ + bRow + fn * 2048 + ksl0);                   \
            b[fn][1] = *(const bf16x8*)(base_ + bRow + fn * 2048 + ksl1);                   \
        }                                                                                   \
    }                                                                                       \
    a_[0][0] = *(const bf16x8*)(base_ + aRow + (Q) * 4096 + ksl0);                          \
    a_[0][1] = *(const bf16x8*)(base_ + aRow + (Q) * 4096 + ksl1);                          \
    a_[1][0] = *(const bf16x8*)(base_ + aRow + (Q) * 4096 + 2048 + ksl0);                   \
    a_[1][1] = *(const bf16x8*)(base_ + aRow + (Q) * 4096 + 2048 + ksl1);                   \
    STAGE_STMT;                                                                             \
    __builtin_amdgcn_s_barrier();                                                           \
    asm volatile("s_waitcnt lgkmcnt(0)" ::: "memory");                                      \
    __builtin_amdgcn_sched_barrier(0);                                                      \
    __builtin_amdgcn_s_setprio(1);                                                          \
    _Pragma("unroll")                                                                       \
    for (int fm = 0; fm < 2; ++fm)                                                          \
        _Pragma("unroll")                                                                   \
        for (int fn = 0; fn < 4; ++fn) {                                                    \
            acc[(Q)*2 + fm][fn] = __builtin_amdgcn_mfma_f32_16x16x32_bf16(                  \
                a_[fm][0], b[fn][0], acc[(Q)*2 + fm][fn], 0, 0, 0);                         \
            acc[(Q)*2 + fm][fn] = __builtin_amdgcn_mfma_f32_16x16x32_bf16(                  \
                a_[fm][1], b[fn][1], acc[(Q)*2 + fm][fn], 0, 0, 0);                         \
        }                                                                                   \
    __builtin_amdgcn_s_setprio(0);                                                          \
    VM_STMT;                                                                                \
    __builtin_amdgcn_s_barrier();                                                           \
} while (0)

#define STORE_Q(Q) do {                                                                     \
    _Pragma("unroll")                                                                       \
    for (int fm = (Q) * 2; fm < (Q) * 2 + 2; ++fm)                                          \
        _Pragma("unroll")                                                                   \
        for (int fn = 0; fn < 4; ++fn)                                                      \
            _Pragma("unroll")                                                               \
            for (int r = 0; r < 4; ++r)                                                     \
                Cb[(size_t)(fm * 16 + r) * N_DIM + fn * 16] = acc[fm][fn][r];               \
} while (0)

    // ---- prologue: t0 complete + t1.{B0,B1,A0}; newest 3 halves may fly ----
    STAGE_HALF(gB0, 32768, 0, 0, 0);
    STAGE_HALF(gB0, 32768, 1, 0, 0);
    STAGE_HALF(gA0, 0,     0, 0, 0);
    STAGE_HALF(gA0, 0,     1, 0, 0);
    STAGE_HALF(gB0, 32768, 0, 1, 1);
    STAGE_HALF(gB0, 32768, 1, 1, 1);
    STAGE_HALF(gA0, 0,     0, 1, 1);
    asm volatile("s_waitcnt vmcnt(6)" ::: "memory");
    __builtin_amdgcn_s_barrier();

    // ---- steady iterations ----
    for (int u = 0; u < NITER - 1; ++u) {
        const int t1 = 2 * u + 1, t2 = 2 * u + 2, t3 = 2 * u + 3;

        PHASE(0, 0, 1, { STAGE_HALF(gA0, 0, 1, t1, 1); }, {});                 // t1.A1
        PHASE(0, 1, 0, { STAGE_HALF(gB0, 32768, 0, t2, 0); }, {});             // t2.B0
        PHASE(0, 2, 0, { STAGE_HALF(gB0, 32768, 1, t2, 0); }, {});             // t2.B1
        PHASE(0, 3, 0, { STAGE_HALF(gA0, 0, 0, t2, 0); },                      // t2.A0
              { asm volatile("s_waitcnt vmcnt(6)" ::: "memory"); });
        PHASE(1, 0, 1, { STAGE_HALF(gA0, 0, 1, t2, 0); }, {});                 // t2.A1
        PHASE(1, 1, 0, { STAGE_HALF(gB0, 32768, 0, t3, 1); }, {});             // t3.B0
        PHASE(1, 2, 0, { STAGE_HALF(gB0, 32768, 1, t3, 1); }, {});             // t3.B1
        PHASE(1, 3, 0, { STAGE_HALF(gA0, 0, 0, t3, 1); },                      // t3.A0
              { asm volatile("s_waitcnt vmcnt(6)" ::: "memory"); });
    }

    // ---- peeled last iteration: progressive quadrant stores in ph5-8 ----
    PHASE(0, 0, 1, { STAGE_HALF(gA0, 0, 1, NT - 1, 1); }, {});                 // final A1
    PHASE(0, 1, 0, {}, {});
    PHASE(0, 2, 0, {}, {});
    PHASE(0, 3, 0, {}, { asm volatile("s_waitcnt vmcnt(0)" ::: "memory"); });  // queue empty
    PHASE(1, 0, 1, {}, { STORE_Q(0); });
    PHASE(1, 1, 0, {}, { STORE_Q(1); });
    PHASE(1, 2, 0, {}, { STORE_Q(2); });
    PHASE(1, 3, 0, {}, { STORE_Q(3); });

#undef STORE_Q
#undef PHASE
#undef STAGE_HALF
}

// ---------------------------------------------------------------------------
extern "C" void kernel_launch(void* const* d_in, const int* in_sizes, int n_in,
                              void* d_out, int out_size, void* d_ws, size_t ws_size,
                              hipStream_t stream) {
    const float* x = (const float*)d_in[0];   // (4,2048,2048) fp32
    const float* W = (const float*)d_in[1];   // (4096,2048) fp32
    float* out = (float*)d_out;               // (4,2048,4096) fp32

    unsigned short* xb = (unsigned short*)d_ws;                                      // 32 MB bf16 x
    unsigned short* wt = (unsigned short*)((char*)d_ws + (size_t)M_DIM * K_DIM * 2); // 16 MB WeffT

    const int cvt_blocks = (M_DIM * K_DIM) / 4 / 256 / 4;   // 1024 fat blocks
    prep_fused<<<N_DIM / 8 + cvt_blocks, 256, 0, stream>>>(x, W, xb, wt);

    dim3 grid((M_DIM / BM) * (N_DIM / BN));   // 512 blocks
    gemm8p<<<grid, 512, 0, stream>>>(xb, wt, out);
}